// Round 1
// baseline (113.100 us; speedup 1.0000x reference)
//
#include <hip/hip_runtime.h>

#define NVID 256
#define DIM 1024

// ---------------------------------------------------------------------------
// K1: segmented mean of embedding rows.
// blocks 0..255   -> video i means over im   -> A[i][:]
// blocks 256..511 -> video i means over s    -> B[i][:]
// 256 threads/block, each owns 4 contiguous floats (float4) of the 1024 cols.
// Segment offset computed per-block from counts staged in LDS.
// Also zeroes d_out (block 0) so K3 can atomicAdd.
// ---------------------------------------------------------------------------
__global__ __launch_bounds__(256) void seg_mean_kernel(
    const float* __restrict__ im, const float* __restrict__ s,
    const int* __restrict__ num_clips, const int* __restrict__ num_caps,
    float* __restrict__ A, float* __restrict__ B, float* __restrict__ out)
{
    const int b = blockIdx.x;
    const int t = threadIdx.x;
    if (b == 0 && t == 0) out[0] = 0.0f;

    const bool isClip = (b < NVID);
    const int vid = isClip ? b : b - NVID;
    const int* cnt = isClip ? num_clips : num_caps;
    const float* src = isClip ? im : s;
    float* dst = isClip ? A : B;

    __shared__ int scnt[NVID];
    scnt[t] = cnt[t];
    __syncthreads();

    // exclusive prefix sum up to vid (uniform loop, LDS broadcast reads)
    int off = 0;
    for (int k = 0; k < vid; ++k) off += scnt[k];
    const int n = scnt[vid];

    const float4* srcv = (const float4*)src + (size_t)off * (DIM / 4) + t;
    float4 acc = make_float4(0.f, 0.f, 0.f, 0.f);
    for (int r = 0; r < n; ++r) {
        float4 v = srcv[(size_t)r * (DIM / 4)];
        acc.x += v.x; acc.y += v.y; acc.z += v.z; acc.w += v.w;
    }
    const float inv = 1.0f / (float)n;
    acc.x *= inv; acc.y *= inv; acc.z *= inv; acc.w *= inv;
    ((float4*)(dst + (size_t)vid * DIM))[t] = acc;
}

// ---------------------------------------------------------------------------
// K2: diag[i] = A[i] . B[i]   (one block per i, block-wide reduction)
// ---------------------------------------------------------------------------
__global__ __launch_bounds__(256) void diag_kernel(
    const float* __restrict__ A, const float* __restrict__ B,
    float* __restrict__ diag)
{
    const int i = blockIdx.x;
    const int t = threadIdx.x;
    float4 a = ((const float4*)(A + (size_t)i * DIM))[t];
    float4 b = ((const float4*)(B + (size_t)i * DIM))[t];
    float p = a.x * b.x + a.y * b.y + a.z * b.z + a.w * b.w;

    for (int o = 32; o > 0; o >>= 1) p += __shfl_down(p, o, 64);

    __shared__ float wsum[4];
    const int wave = t >> 6, lane = t & 63;
    if (lane == 0) wsum[wave] = p;
    __syncthreads();
    if (t == 0) diag[i] = wsum[0] + wsum[1] + wsum[2] + wsum[3];
}

// ---------------------------------------------------------------------------
// K3: fused S = A @ B^T (256x256x1024, fp32 vector ALU) + hinge loss + reduce.
// Grid 16x16 blocks; each block computes a 16x16 tile of S via LDS-staged
// k-chunks (KC=64). Thread (ty,tx) owns one S element. LDS padded +1 to
// break the 16-way bank conflict on Bs[tx][k].
// ---------------------------------------------------------------------------
__global__ __launch_bounds__(256) void loss_kernel(
    const float* __restrict__ A, const float* __restrict__ B,
    const float* __restrict__ diag, float* __restrict__ out)
{
    constexpr int KC = 64;
    __shared__ float As[16][KC + 1];
    __shared__ float Bs[16][KC + 1];

    const int t = threadIdx.x;
    const int tx = t & 15, ty = t >> 4;
    const int i0 = blockIdx.y * 16, j0 = blockIdx.x * 16;

    // cooperative load mapping: thread t loads 4 floats of row (t>>4)
    const int lrow = t >> 4;
    const int lcol = (t & 15) * 4;

    float acc = 0.f;
    for (int kb = 0; kb < DIM; kb += KC) {
        float4 va = *(const float4*)(A + (size_t)(i0 + lrow) * DIM + kb + lcol);
        float4 vb = *(const float4*)(B + (size_t)(j0 + lrow) * DIM + kb + lcol);
        As[lrow][lcol + 0] = va.x; As[lrow][lcol + 1] = va.y;
        As[lrow][lcol + 2] = va.z; As[lrow][lcol + 3] = va.w;
        Bs[lrow][lcol + 0] = vb.x; Bs[lrow][lcol + 1] = vb.y;
        Bs[lrow][lcol + 2] = vb.z; Bs[lrow][lcol + 3] = vb.w;
        __syncthreads();
#pragma unroll
        for (int k = 0; k < KC; ++k) acc += As[ty][k] * Bs[tx][k];
        __syncthreads();
    }

    const int i = i0 + ty, j = j0 + tx;
    float v = 0.f;
    if (i != j) {
        const float dI = diag[i];
        const float dJ = diag[j];
        v = fmaxf(acc - dI, 0.f) + fmaxf(acc - dJ, 0.f);
    }

    for (int o = 32; o > 0; o >>= 1) v += __shfl_down(v, o, 64);
    __shared__ float wsum[4];
    const int wave = t >> 6, lane = t & 63;
    if (lane == 0) wsum[wave] = v;
    __syncthreads();
    if (t == 0) atomicAdd(out, wsum[0] + wsum[1] + wsum[2] + wsum[3]);
}

// ---------------------------------------------------------------------------
extern "C" void kernel_launch(void* const* d_in, const int* in_sizes, int n_in,
                              void* d_out, int out_size, void* d_ws, size_t ws_size,
                              hipStream_t stream) {
    const float* im    = (const float*)d_in[0];
    const float* s     = (const float*)d_in[1];
    const int*   nclip = (const int*)d_in[2];
    const int*   ncap  = (const int*)d_in[3];
    float* out = (float*)d_out;

    float* A    = (float*)d_ws;            // 256*1024 floats = 1 MB
    float* B    = A + NVID * DIM;          // 1 MB
    float* diag = B + NVID * DIM;          // 1 KB

    seg_mean_kernel<<<2 * NVID, 256, 0, stream>>>(im, s, nclip, ncap, A, B, out);
    diag_kernel<<<NVID, 256, 0, stream>>>(A, B, diag);
    loss_kernel<<<dim3(16, 16), 256, 0, stream>>>(A, B, diag, out);
}

// Round 2
// 95.526 us; speedup vs baseline: 1.1840x; 1.1840x over previous
//
#include <hip/hip_runtime.h>

#define NVID 256
#define DIM 1024

__device__ inline void acc4(float4& a, const float4& v) {
    a.x += v.x; a.y += v.y; a.z += v.z; a.w += v.w;
}

// ---------------------------------------------------------------------------
// K1: segmented mean of embedding rows.
// blocks 0..255   -> video i means over im   -> A[i][:]
// blocks 256..511 -> video i means over s    -> B[i][:]
// Row loop unrolled x4 with independent accumulators -> 4 outstanding
// float4 loads per thread (latency hiding; runtime trip count blocks
// compiler pipelining otherwise). Also zeroes d_out for K3's atomicAdd.
// ---------------------------------------------------------------------------
__global__ __launch_bounds__(256) void seg_mean_kernel(
    const float* __restrict__ im, const float* __restrict__ s,
    const int* __restrict__ num_clips, const int* __restrict__ num_caps,
    float* __restrict__ A, float* __restrict__ B, float* __restrict__ out)
{
    const int b = blockIdx.x;
    const int t = threadIdx.x;
    if (b == 0 && t == 0) out[0] = 0.0f;

    const bool isClip = (b < NVID);
    const int vid = isClip ? b : b - NVID;
    const int* cnt = isClip ? num_clips : num_caps;
    const float* src = isClip ? im : s;
    float* dst = isClip ? A : B;

    __shared__ int scnt[NVID];
    scnt[t] = cnt[t];
    __syncthreads();

    int off = 0;
    for (int k = 0; k < vid; ++k) off += scnt[k];
    const int n = scnt[vid];

    const float4* srcv = (const float4*)src + (size_t)off * (DIM / 4) + t;
    float4 a0 = {0,0,0,0}, a1 = {0,0,0,0}, a2 = {0,0,0,0}, a3 = {0,0,0,0};
    int r = 0;
    for (; r + 4 <= n; r += 4) {
        float4 v0 = srcv[(size_t)(r + 0) * (DIM / 4)];
        float4 v1 = srcv[(size_t)(r + 1) * (DIM / 4)];
        float4 v2 = srcv[(size_t)(r + 2) * (DIM / 4)];
        float4 v3 = srcv[(size_t)(r + 3) * (DIM / 4)];
        acc4(a0, v0); acc4(a1, v1); acc4(a2, v2); acc4(a3, v3);
    }
    for (; r < n; ++r) {
        float4 v = srcv[(size_t)r * (DIM / 4)];
        acc4(a0, v);
    }
    acc4(a0, a1); acc4(a2, a3); acc4(a0, a2);
    const float inv = 1.0f / (float)n;
    a0.x *= inv; a0.y *= inv; a0.z *= inv; a0.w *= inv;
    ((float4*)(dst + (size_t)vid * DIM))[t] = a0;
}

// ---------------------------------------------------------------------------
// K2: diag[i] = A[i] . B[i]   (one block per i, block-wide reduction)
// ---------------------------------------------------------------------------
__global__ __launch_bounds__(256) void diag_kernel(
    const float* __restrict__ A, const float* __restrict__ B,
    float* __restrict__ diag)
{
    const int i = blockIdx.x;
    const int t = threadIdx.x;
    float4 a = ((const float4*)(A + (size_t)i * DIM))[t];
    float4 b = ((const float4*)(B + (size_t)i * DIM))[t];
    float p = a.x * b.x + a.y * b.y + a.z * b.z + a.w * b.w;

    for (int o = 32; o > 0; o >>= 1) p += __shfl_down(p, o, 64);

    __shared__ float wsum[4];
    const int wave = t >> 6, lane = t & 63;
    if (lane == 0) wsum[wave] = p;
    __syncthreads();
    if (t == 0) diag[i] = wsum[0] + wsum[1] + wsum[2] + wsum[3];
}

// ---------------------------------------------------------------------------
// K3: fused S = A @ B^T (256x256x1024 fp32 vector ALU) + hinge loss + reduce.
// Grid 16x16; each block computes a 16x16 tile.
//   - LDS row stride 68 floats (272 B, 16B-aligned) -> ds_read_b128 legal,
//     <=2-way bank aliasing (free). (KC+1 padding gave 260 B stride which
//     silently forced scalar ds_read_b32.)
//   - Double-buffered LDS: next chunk's global float4 load issues before
//     compute, LDS store after compute, ONE barrier per chunk.
// ---------------------------------------------------------------------------
__global__ __launch_bounds__(256) void loss_kernel(
    const float* __restrict__ A, const float* __restrict__ B,
    const float* __restrict__ diag, float* __restrict__ out)
{
    constexpr int KC = 64;
    constexpr int LDW = KC + 4;           // 68 floats = 272 B, 16B-aligned
    __shared__ float As[2][16][LDW];
    __shared__ float Bs[2][16][LDW];

    const int t = threadIdx.x;
    const int tx = t & 15, ty = t >> 4;
    const int i0 = blockIdx.y * 16, j0 = blockIdx.x * 16;

    const int lrow = t >> 4;              // 0..15
    const int lcol = (t & 15) * 4;        // 0..60

    const float* Arow = A + (size_t)(i0 + lrow) * DIM + lcol;
    const float* Brow = B + (size_t)(j0 + lrow) * DIM + lcol;

    // preload chunk 0
    float4 va = *(const float4*)(Arow + 0);
    float4 vb = *(const float4*)(Brow + 0);
    *(float4*)&As[0][lrow][lcol] = va;
    *(float4*)&Bs[0][lrow][lcol] = vb;
    __syncthreads();

    float acc = 0.f;
    constexpr int NCHUNK = DIM / KC;      // 16
    for (int c = 0; c < NCHUNK; ++c) {
        const int cur = c & 1;
        if (c + 1 < NCHUNK) {
            va = *(const float4*)(Arow + (c + 1) * KC);
            vb = *(const float4*)(Brow + (c + 1) * KC);
        }
#pragma unroll
        for (int k = 0; k < KC; k += 4) {
            float4 fa = *(const float4*)&As[cur][ty][k];
            float4 fb = *(const float4*)&Bs[cur][tx][k];
            acc += fa.x * fb.x + fa.y * fb.y + fa.z * fb.z + fa.w * fb.w;
        }
        if (c + 1 < NCHUNK) {
            *(float4*)&As[cur ^ 1][lrow][lcol] = va;
            *(float4*)&Bs[cur ^ 1][lrow][lcol] = vb;
        }
        __syncthreads();
    }

    const int i = i0 + ty, j = j0 + tx;
    float v = 0.f;
    if (i != j) {
        const float dI = diag[i];
        const float dJ = diag[j];
        v = fmaxf(acc - dI, 0.f) + fmaxf(acc - dJ, 0.f);
    }

    for (int o = 32; o > 0; o >>= 1) v += __shfl_down(v, o, 64);
    __shared__ float wsum[4];
    const int wave = t >> 6, lane = t & 63;
    if (lane == 0) wsum[wave] = v;
    __syncthreads();
    if (t == 0) atomicAdd(out, wsum[0] + wsum[1] + wsum[2] + wsum[3]);
}

// ---------------------------------------------------------------------------
extern "C" void kernel_launch(void* const* d_in, const int* in_sizes, int n_in,
                              void* d_out, int out_size, void* d_ws, size_t ws_size,
                              hipStream_t stream) {
    const float* im    = (const float*)d_in[0];
    const float* s     = (const float*)d_in[1];
    const int*   nclip = (const int*)d_in[2];
    const int*   ncap  = (const int*)d_in[3];
    float* out = (float*)d_out;

    float* A    = (float*)d_ws;            // 1 MB
    float* B    = A + NVID * DIM;          // 1 MB
    float* diag = B + NVID * DIM;          // 1 KB

    seg_mean_kernel<<<2 * NVID, 256, 0, stream>>>(im, s, nclip, ncap, A, B, out);
    diag_kernel<<<NVID, 256, 0, stream>>>(A, B, diag);
    loss_kernel<<<dim3(16, 16), 256, 0, stream>>>(A, B, diag, out);
}

// Round 3
// 87.469 us; speedup vs baseline: 1.2930x; 1.0921x over previous
//
#include <hip/hip_runtime.h>
#include <hip/hip_bf16.h>

#define NVID 256
#define DIM 1024

typedef short bf16x8 __attribute__((ext_vector_type(8)));
typedef float f32x4 __attribute__((ext_vector_type(4)));

__device__ inline void acc4(float4& a, const float4& v) {
    a.x += v.x; a.y += v.y; a.z += v.z; a.w += v.w;
}

__device__ inline unsigned short f2bf(float f) {
    __hip_bfloat16 h = __float2bfloat16(f);   // RNE
    unsigned short u;
    __builtin_memcpy(&u, &h, 2);
    return u;
}

__device__ inline float bf2f(unsigned short u) {
    return __uint_as_float(((unsigned)u) << 16);
}

// ---------------------------------------------------------------------------
// K1: segmented mean -> bf16 A/B.
// blocks 0..255 -> mean over im -> Ab[i][:]; 256..511 -> mean over s -> Bb.
// Row loop unrolled x8 (n >= 8 guaranteed) with 4 accumulators -> 8
// outstanding float4 loads/thread for latency hiding. Zeroes d_out.
// ---------------------------------------------------------------------------
__global__ __launch_bounds__(256) void seg_mean_kernel(
    const float* __restrict__ im, const float* __restrict__ s,
    const int* __restrict__ num_clips, const int* __restrict__ num_caps,
    unsigned short* __restrict__ Ab, unsigned short* __restrict__ Bb,
    float* __restrict__ out)
{
    const int b = blockIdx.x;
    const int t = threadIdx.x;
    if (b == 0 && t == 0) out[0] = 0.0f;

    const bool isClip = (b < NVID);
    const int vid = isClip ? b : b - NVID;
    const int* cnt = isClip ? num_clips : num_caps;
    const float* src = isClip ? im : s;
    unsigned short* dst = isClip ? Ab : Bb;

    __shared__ int scnt[NVID];
    scnt[t] = cnt[t];
    __syncthreads();

    int off = 0;
    for (int k = 0; k < vid; ++k) off += scnt[k];
    const int n = scnt[vid];

    const float4* srcv = (const float4*)src + (size_t)off * (DIM / 4) + t;
    float4 a0 = {0,0,0,0}, a1 = {0,0,0,0}, a2 = {0,0,0,0}, a3 = {0,0,0,0};
    int r = 0;
    for (; r + 8 <= n; r += 8) {
        float4 v0 = srcv[(size_t)(r + 0) * (DIM / 4)];
        float4 v1 = srcv[(size_t)(r + 1) * (DIM / 4)];
        float4 v2 = srcv[(size_t)(r + 2) * (DIM / 4)];
        float4 v3 = srcv[(size_t)(r + 3) * (DIM / 4)];
        float4 v4 = srcv[(size_t)(r + 4) * (DIM / 4)];
        float4 v5 = srcv[(size_t)(r + 5) * (DIM / 4)];
        float4 v6 = srcv[(size_t)(r + 6) * (DIM / 4)];
        float4 v7 = srcv[(size_t)(r + 7) * (DIM / 4)];
        acc4(a0, v0); acc4(a1, v1); acc4(a2, v2); acc4(a3, v3);
        acc4(a0, v4); acc4(a1, v5); acc4(a2, v6); acc4(a3, v7);
    }
    for (; r < n; ++r) {
        float4 v = srcv[(size_t)r * (DIM / 4)];
        acc4(a0, v);
    }
    acc4(a0, a1); acc4(a2, a3); acc4(a0, a2);
    const float inv = 1.0f / (float)n;
    a0.x *= inv; a0.y *= inv; a0.z *= inv; a0.w *= inv;

    ushort4 ov;
    ov.x = f2bf(a0.x); ov.y = f2bf(a0.y); ov.z = f2bf(a0.z); ov.w = f2bf(a0.w);
    ((ushort4*)(dst + (size_t)vid * DIM))[t] = ov;
}

// ---------------------------------------------------------------------------
// K2: diag[i] = Ab[i] . Bb[i]  (bf16 in, fp32 accumulate, block reduction)
// ---------------------------------------------------------------------------
__global__ __launch_bounds__(256) void diag_kernel(
    const unsigned short* __restrict__ Ab, const unsigned short* __restrict__ Bb,
    float* __restrict__ diag)
{
    const int i = blockIdx.x;
    const int t = threadIdx.x;
    ushort4 ua = ((const ushort4*)(Ab + (size_t)i * DIM))[t];
    ushort4 ub = ((const ushort4*)(Bb + (size_t)i * DIM))[t];
    float p = bf2f(ua.x) * bf2f(ub.x) + bf2f(ua.y) * bf2f(ub.y)
            + bf2f(ua.z) * bf2f(ub.z) + bf2f(ua.w) * bf2f(ub.w);

    for (int o = 32; o > 0; o >>= 1) p += __shfl_down(p, o, 64);

    __shared__ float wsum[4];
    const int wave = t >> 6, lane = t & 63;
    if (lane == 0) wsum[wave] = p;
    __syncthreads();
    if (t == 0) diag[i] = wsum[0] + wsum[1] + wsum[2] + wsum[3];
}

// ---------------------------------------------------------------------------
// K3: S = A @ B^T via mfma_f32_16x16x32_bf16, fused hinge + reduce.
// One wave per 16x16 tile; grid 16x16. Fragments loaded straight from
// global (A,B bf16 = 1 MB total -> L2-resident; 16 B/lane contiguous).
//   A-frag: A[i0 + (lane&15)][kb + (lane>>4)*8 + j]   (m120-verified layout)
//   B-frag: B[j0 + (lane&15)][kb + (lane>>4)*8 + j]   (gemm_bt symmetric)
//   C/D:    S[i0 + (lane>>4)*4 + reg][j0 + (lane&15)] (m89/m91-verified)
// ---------------------------------------------------------------------------
__global__ __launch_bounds__(64) void loss_kernel(
    const unsigned short* __restrict__ Ab, const unsigned short* __restrict__ Bb,
    const float* __restrict__ diag, float* __restrict__ out)
{
    const int lane = threadIdx.x;
    const int i0 = blockIdx.y * 16, j0 = blockIdx.x * 16;
    const int m = lane & 15, q = lane >> 4;

    const unsigned short* Ap = Ab + (size_t)(i0 + m) * DIM + q * 8;
    const unsigned short* Bp = Bb + (size_t)(j0 + m) * DIM + q * 8;

    f32x4 acc = {0.f, 0.f, 0.f, 0.f};
#pragma unroll
    for (int kb = 0; kb < DIM; kb += 32) {
        bf16x8 a = *(const bf16x8*)(Ap + kb);
        bf16x8 b = *(const bf16x8*)(Bp + kb);
        acc = __builtin_amdgcn_mfma_f32_16x16x32_bf16(a, b, acc, 0, 0, 0);
    }

    const int j = j0 + m;
    const float dj = diag[j];
    const float4 di = *(const float4*)&diag[i0 + q * 4];
    const float dia[4] = {di.x, di.y, di.z, di.w};

    float v = 0.f;
#pragma unroll
    for (int r = 0; r < 4; ++r) {
        const int i = i0 + q * 4 + r;
        if (i != j) {
            const float sv = acc[r];
            v += fmaxf(sv - dia[r], 0.f) + fmaxf(sv - dj, 0.f);
        }
    }

    for (int o = 32; o > 0; o >>= 1) v += __shfl_down(v, o, 64);
    if (lane == 0) atomicAdd(out, v);
}

// ---------------------------------------------------------------------------
extern "C" void kernel_launch(void* const* d_in, const int* in_sizes, int n_in,
                              void* d_out, int out_size, void* d_ws, size_t ws_size,
                              hipStream_t stream) {
    const float* im    = (const float*)d_in[0];
    const float* s     = (const float*)d_in[1];
    const int*   nclip = (const int*)d_in[2];
    const int*   ncap  = (const int*)d_in[3];
    float* out = (float*)d_out;

    unsigned short* Ab = (unsigned short*)d_ws;       // 512 KB
    unsigned short* Bb = Ab + NVID * DIM;             // 512 KB
    float* diag = (float*)(Bb + NVID * DIM);          // 1 KB

    seg_mean_kernel<<<2 * NVID, 256, 0, stream>>>(im, s, nclip, ncap, Ab, Bb, out);
    diag_kernel<<<NVID, 256, 0, stream>>>(Ab, Bb, diag);
    loss_kernel<<<dim3(16, 16), 64, 0, stream>>>(Ab, Bb, diag, out);
}

// Round 4
// 86.332 us; speedup vs baseline: 1.3100x; 1.0132x over previous
//
#include <hip/hip_runtime.h>
#include <hip/hip_bf16.h>

#define NVID 256
#define DIM 1024

typedef short bf16x8 __attribute__((ext_vector_type(8)));
typedef float f32x4 __attribute__((ext_vector_type(4)));

__device__ inline void acc4(float4& a, const float4& v) {
    a.x += v.x; a.y += v.y; a.z += v.z; a.w += v.w;
}

__device__ inline unsigned short f2bf(float f) {
    __hip_bfloat16 h = __float2bfloat16(f);   // RNE
    unsigned short u;
    __builtin_memcpy(&u, &h, 2);
    return u;
}

__device__ inline float bf2f(unsigned short u) {
    return __uint_as_float(((unsigned)u) << 16);
}

// 8-deep unrolled segmented row-sum (n >= 8 guaranteed by problem: 8+(i%17)).
__device__ inline float4 mean_rows(const float* __restrict__ src, int off, int n, int t) {
    const float4* srcv = (const float4*)src + (size_t)off * (DIM / 4) + t;
    float4 a0 = {0,0,0,0}, a1 = {0,0,0,0}, a2 = {0,0,0,0}, a3 = {0,0,0,0};
    int r = 0;
    for (; r + 8 <= n; r += 8) {
        float4 v0 = srcv[(size_t)(r + 0) * (DIM / 4)];
        float4 v1 = srcv[(size_t)(r + 1) * (DIM / 4)];
        float4 v2 = srcv[(size_t)(r + 2) * (DIM / 4)];
        float4 v3 = srcv[(size_t)(r + 3) * (DIM / 4)];
        float4 v4 = srcv[(size_t)(r + 4) * (DIM / 4)];
        float4 v5 = srcv[(size_t)(r + 5) * (DIM / 4)];
        float4 v6 = srcv[(size_t)(r + 6) * (DIM / 4)];
        float4 v7 = srcv[(size_t)(r + 7) * (DIM / 4)];
        acc4(a0, v0); acc4(a1, v1); acc4(a2, v2); acc4(a3, v3);
        acc4(a0, v4); acc4(a1, v5); acc4(a2, v6); acc4(a3, v7);
    }
    for (; r < n; ++r) acc4(a0, srcv[(size_t)r * (DIM / 4)]);
    acc4(a0, a1); acc4(a2, a3); acc4(a0, a2);
    const float inv = 1.0f / (float)n;
    a0.x *= inv; a0.y *= inv; a0.z *= inv; a0.w *= inv;
    return a0;
}

// ---------------------------------------------------------------------------
// K1: block i computes BOTH the clip-mean A[i] and cap-mean B[i] (bf16 out),
// then diag[i] = A[i].B[i] in-register (block reduction) — K2 eliminated.
// Thread t owns 4 contiguous cols. Zeroes d_out for K3's atomicAdd.
// ---------------------------------------------------------------------------
__global__ __launch_bounds__(256) void mean_diag_kernel(
    const float* __restrict__ im, const float* __restrict__ s,
    const int* __restrict__ num_clips, const int* __restrict__ num_caps,
    unsigned short* __restrict__ Ab, unsigned short* __restrict__ Bb,
    float* __restrict__ diag, float* __restrict__ out)
{
    const int i = blockIdx.x;
    const int t = threadIdx.x;
    if (i == 0 && t == 0) out[0] = 0.0f;

    __shared__ int sc[NVID], sp[NVID];
    sc[t] = num_clips[t];
    sp[t] = num_caps[t];
    __syncthreads();

    int offc = 0, offp = 0;
    for (int k = 0; k < i; ++k) { offc += sc[k]; offp += sp[k]; }
    const int nc = sc[i], np = sp[i];

    float4 am = mean_rows(im, offc, nc, t);
    float4 bm = mean_rows(s,  offp, np, t);

    ushort4 ua, ub;
    ua.x = f2bf(am.x); ua.y = f2bf(am.y); ua.z = f2bf(am.z); ua.w = f2bf(am.w);
    ub.x = f2bf(bm.x); ub.y = f2bf(bm.y); ub.z = f2bf(bm.z); ub.w = f2bf(bm.w);
    ((ushort4*)(Ab + (size_t)i * DIM))[t] = ua;
    ((ushort4*)(Bb + (size_t)i * DIM))[t] = ub;

    // diag from the bf16-rounded values (consistent with K3's bf16 GEMM)
    float p = bf2f(ua.x) * bf2f(ub.x) + bf2f(ua.y) * bf2f(ub.y)
            + bf2f(ua.z) * bf2f(ub.z) + bf2f(ua.w) * bf2f(ub.w);
    for (int o = 32; o > 0; o >>= 1) p += __shfl_down(p, o, 64);

    __shared__ float wsum[4];
    const int wave = t >> 6, lane = t & 63;
    if (lane == 0) wsum[wave] = p;
    __syncthreads();
    if (t == 0) diag[i] = wsum[0] + wsum[1] + wsum[2] + wsum[3];
}

// ---------------------------------------------------------------------------
// K3: S = A @ B^T via mfma_f32_16x16x32_bf16, fused hinge + reduce.
// One wave per 16x16 tile; grid 16x16. Fragments straight from global
// (A,B bf16 = 1 MB total -> L2-resident; 16 B/lane contiguous).
// ---------------------------------------------------------------------------
__global__ __launch_bounds__(64) void loss_kernel(
    const unsigned short* __restrict__ Ab, const unsigned short* __restrict__ Bb,
    const float* __restrict__ diag, float* __restrict__ out)
{
    const int lane = threadIdx.x;
    const int i0 = blockIdx.y * 16, j0 = blockIdx.x * 16;
    const int m = lane & 15, q = lane >> 4;

    const unsigned short* Ap = Ab + (size_t)(i0 + m) * DIM + q * 8;
    const unsigned short* Bp = Bb + (size_t)(j0 + m) * DIM + q * 8;

    f32x4 acc = {0.f, 0.f, 0.f, 0.f};
#pragma unroll
    for (int kb = 0; kb < DIM; kb += 32) {
        bf16x8 a = *(const bf16x8*)(Ap + kb);
        bf16x8 b = *(const bf16x8*)(Bp + kb);
        acc = __builtin_amdgcn_mfma_f32_16x16x32_bf16(a, b, acc, 0, 0, 0);
    }

    const int j = j0 + m;
    const float dj = diag[j];
    const float4 di = *(const float4*)&diag[i0 + q * 4];
    const float dia[4] = {di.x, di.y, di.z, di.w};

    float v = 0.f;
#pragma unroll
    for (int r = 0; r < 4; ++r) {
        const int i = i0 + q * 4 + r;
        if (i != j) {
            const float sv = acc[r];
            v += fmaxf(sv - dia[r], 0.f) + fmaxf(sv - dj, 0.f);
        }
    }

    for (int o = 32; o > 0; o >>= 1) v += __shfl_down(v, o, 64);
    if (lane == 0) atomicAdd(out, v);
}

// ---------------------------------------------------------------------------
extern "C" void kernel_launch(void* const* d_in, const int* in_sizes, int n_in,
                              void* d_out, int out_size, void* d_ws, size_t ws_size,
                              hipStream_t stream) {
    const float* im    = (const float*)d_in[0];
    const float* s     = (const float*)d_in[1];
    const int*   nclip = (const int*)d_in[2];
    const int*   ncap  = (const int*)d_in[3];
    float* out = (float*)d_out;

    unsigned short* Ab = (unsigned short*)d_ws;       // 512 KB
    unsigned short* Bb = Ab + NVID * DIM;             // 512 KB
    float* diag = (float*)(Bb + NVID * DIM);          // 1 KB

    mean_diag_kernel<<<NVID, 256, 0, stream>>>(im, s, nclip, ncap, Ab, Bb, diag, out);
    loss_kernel<<<dim3(16, 16), 64, 0, stream>>>(Ab, Bb, diag, out);
}